// Round 8
// baseline (108.474 us; speedup 1.0000x reference)
//
#include <hip/hip_runtime.h>

// rmsdLoss via associative affine scan — R18.
// R17 post-mortem: atomic-floor CONFIRMED (dur_us 118.9->108.2; rmsd_kernel
// now below the 41us harness fills in top-5, i.e. ~30us). COROLLARY: the
// ~43us floor masked ALL R10-R16 comparisons — R16's coalesced-staging "null"
// falsified nothing (both sides pinned at the floor). The L1/TA arithmetic
// stands: strided chunk loads = ~1056 line-transactions/wave (~67KB L1
// traffic for 8.5KB useful) -> ~14us shared L1/TA occupancy per CU, about
// half the remaining ~30us. Coalesced staging cuts it 8x.
// R18 = R17 (ws store + reduce kernel, no atomics) + R16's staging, one
// variable: 256 threads stage both rows tid-linearly into LDS (256B/instr,
// 4 lines/wave-instr), chunk values read from swizzled LDS (~4-way max,
// ~741K conflict-cycles = ~0.3us), pos arena aliases the dead Ls[0].
// Predicted: dur_us 108.2 -> ~100-104 (rmsd ~30 -> ~22-25us). If flat ->
// L1 theory dead, kernel is VALU-issue-bound -> pivot to CHUNK=16 (halves
// total scan work; staging already supplies inputs without 65 live regs).

#define LROW  4087
#define NSTEP 1021
#define NROW  2048
#define CHUNK 8
#define EPSF  1e-6f
#define INVMEAN (1.0f / (2048.0f * 1024.0f * 3.0f))
#define SWZ(i) ((i) ^ ((((i) >> 5) & 15) << 1))

__device__ __forceinline__ float frcp(float x){ return __builtin_amdgcn_rcpf(x); }
__device__ __forceinline__ float frsq(float x){ return __builtin_amdgcn_rsqf(x); }

struct Xf { float f[12]; };  // COLUMN-major: f[0..2]=c0, f[3..5]=c1, f[6..8]=c2, f[9..11]=t

__device__ __forceinline__ Xf xident(){
  Xf X;
  X.f[0]=1.f; X.f[1]=0.f; X.f[2]=0.f;
  X.f[3]=0.f; X.f[4]=1.f; X.f[5]=0.f;
  X.f[6]=0.f; X.f[7]=0.f; X.f[8]=1.f;
  X.f[9]=0.f; X.f[10]=0.f; X.f[11]=0.f;
  return X;
}

// A applied first, then B: C.M = A.M*B.M (columns), C.t = A.t + A.M*B.t
__device__ __forceinline__ Xf xcombine(const Xf& A, const Xf& B){
  Xf C;
  #pragma unroll
  for (int c3 = 0; c3 < 12; c3 += 3){
    const float bx = B.f[c3], by = B.f[c3+1], bz = B.f[c3+2];
    C.f[c3]   = A.f[0]*bx + A.f[3]*by + A.f[6]*bz;
    C.f[c3+1] = A.f[1]*bx + A.f[4]*by + A.f[7]*bz;
    C.f[c3+2] = A.f[2]*bx + A.f[5]*by + A.f[8]*bz;
  }
  C.f[9] += A.f[9]; C.f[10] += A.f[10]; C.f[11] += A.f[11];
  return C;
}

__device__ __forceinline__ void xstepP(Xf& X, float Px, float Py, float Pz){
  const float l2 = Px*Px + Py*Py + Pz*Pz;
  const float q  = frsq(l2);
  const float hx = q*Px, hy = q*Py, hz = q*Pz;
  const float ist = frsq(fmaxf(hy*hy + hz*hz, 1e-12f));   // 1/st, cancellation-free
  const float ux = X.f[0]*Px + X.f[3]*Py + X.f[6]*Pz;
  const float uy = X.f[1]*Px + X.f[4]*Py + X.f[7]*Pz;
  const float uz = X.f[2]*Px + X.f[5]*Py + X.f[8]*Pz;
  X.f[9] += ux; X.f[10] += uy; X.f[11] += uz;
  const float n0x = q*ux, n0y = q*uy, n0z = q*uz;
  const float n1x = ist*(hx*n0x - X.f[0]);
  const float n1y = ist*(hx*n0y - X.f[1]);
  const float n1z = ist*(hx*n0z - X.f[2]);
  const float n2x = ist*(hy*X.f[6] - hz*X.f[3]);
  const float n2y = ist*(hy*X.f[7] - hz*X.f[4]);
  const float n2z = ist*(hy*X.f[8] - hz*X.f[5]);
  X.f[0]=n0x; X.f[1]=n0y; X.f[2]=n0z;
  X.f[3]=n1x; X.f[4]=n1y; X.f[5]=n1z;
  X.f[6]=n2x; X.f[7]=n2y; X.f[8]=n2z;
}

__device__ __forceinline__ void xinitP(Xf& X, float Px, float Py, float Pz){
  const float l2 = Px*Px + Py*Py + Pz*Pz;
  const float q  = frsq(l2);
  const float hx = q*Px, hy = q*Py, hz = q*Pz;
  const float s2 = fmaxf(hy*hy + hz*hz, 1e-12f);
  const float ist = frsq(s2);
  const float st  = s2 * ist;
  X.f[0]=hx;        X.f[1]=hy;          X.f[2]=hz;
  X.f[3]=-st;       X.f[4]=hx*hy*ist;   X.f[5]=hx*hz*ist;
  X.f[6]=0.f;       X.f[7]=-hz*ist;     X.f[8]=hy*ist;
  X.f[9]=Px;        X.f[10]=Py;        X.f[11]=Pz;
}

__global__ void __launch_bounds__(256, 4)
rmsd_kernel(const float* __restrict__ pred, const float* __restrict__ targ,
            float* __restrict__ ws){
  __shared__ float Ls[2][4096];       // 32 KB staging; Ls[0] reused as pos arena
  __shared__ float Tbuf[2][12];       // per-chain half-0 inclusive totals
  __shared__ float ini[3];            // pred a1x, a2x, a2y
  __shared__ float part;              // targ half-1 reduced partial

  const int row  = blockIdx.x;
  const int tid  = threadIdx.x;
  const int ln   = tid & 63;
  const int wv   = tid >> 6;          // 0..3
  const int c    = wv >> 1;           // 0 = pred, 1 = targ
  const int half = wv & 1;            // which half of the chain
  const int lid  = (half << 6) | ln;  // 0..127 lane-in-chain
  const int j0   = lid * CHUNK;       // first step owned (<= 1016)

  const float* __restrict__ vp = pred + (size_t)row * LROW;
  const float* __restrict__ vt = targ + (size_t)row * LROW;
  const float* __restrict__ v  = c ? vt : vp;
  const float cl = c ? 1e30f : 1.0f;  // reference clips pred only

  // ---- coalesced staging: tid-linear, 256B/instr; swizzled LDS dest ----
  #pragma unroll
  for (int i = 0; i < 15; ++i){
    const int idx = tid + (i << 8);
    Ls[0][SWZ(idx)] = vp[idx];
  }
  { const int idx = tid + (15 << 8); if (idx < LROW) Ls[0][SWZ(idx)] = vp[idx]; }
  #pragma unroll
  for (int i = 0; i < 15; ++i){
    const int idx = tid + (i << 8);
    Ls[1][SWZ(idx)] = vt[idx];
  }
  { const int idx = tid + (15 << 8); if (idx < LROW) Ls[1][SWZ(idx)] = vt[idx]; }

  // broadcast fold inputs (wave-uniform -> scalar loads)
  const float rb0 = fminf(fmaxf(v[3064], -cl), cl);
  const float rd0 = fminf(fmaxf(v[2042], -cl), cl);
  const float rb1w= fminf(fmaxf(v[3065], -cl), cl);

  __syncthreads();

  // ---- per-lane chunk values from LDS (~4-way conflicts max) ----
  const float* __restrict__ Lc = Ls[c];
  float s0[CHUNK], s1[CHUNK], dd[CHUNK], bv[CHUNK+1];
  #pragma unroll
  for (int k = 0; k < CHUNK; ++k){
    s0[k] = Lc[SWZ(2*(j0+k))];
    s1[k] = Lc[SWZ(2*(j0+k)+1)];
    dd[k] = Lc[SWZ(2043 + j0 + k)];
  }
  #pragma unroll
  for (int m = 0; m <= CHUNK; ++m){
    int ix = 3065 + j0 + m;
    if (ix > 4086) ix = 4086;        // tail lane clamp (garbage steps guarded)
    bv[m] = Lc[SWZ(ix)];
  }
  #pragma unroll
  for (int m = 0; m <= CHUNK; ++m)
    bv[m] = fmaf(fminf(fmaxf(bv[m], -cl), cl), 1.05f, 1.95f);

  // ---- per-step P in lane-local frame ----
  float Px[CHUNK], Py[CHUNK], Pz[CHUNK];
  #pragma unroll
  for (int k = 0; k < CHUNK; ++k){
    const float a0 = fminf(fmaxf(s0[k], -cl), cl);
    const float a1 = fminf(fmaxf(s1[k], -cl), cl);
    const float d  = fmaf(fminf(fmaxf(dd[k], -cl), cl), 1.75f, 3.25f);
    const float b1 = bv[k], b2 = bv[k+1];
    float ct = (b1*b1 + b2*b2 - d*d) * frcp(2.0f*b1*b2);
    ct = fminf(fmaxf(ct, -1.0f + EPSF), 1.0f - EPSF);
    const float st = sqrtf(fmaxf(1.0f - ct*ct, 0.0f));
    const float r2 = a0*a0 + a1*a1;
    const bool ok = r2 > 1e-36f;
    const float ir = ok ? frcp(sqrtf(r2)) : 0.0f;
    const float scv = a0 * ir;
    const float ccv = ok ? a1 * ir : 1.0f;
    Px[k] = -b2 * ct;
    Py[k] = b2 * st * ccv;
    Pz[k] = b2 * st * scv;
  }

  // ---- per-lane chunk compose (8 steps), snapshot local-prefix translations ----
  Xf X;
  float tl[CHUNK][3];
  xinitP(X, Px[0], Py[0], Pz[0]);
  tl[0][0]=X.f[9]; tl[0][1]=X.f[10]; tl[0][2]=X.f[11];
  #pragma unroll
  for (int k = 1; k < CHUNK; ++k){
    if (j0 + k < NSTEP) xstepP(X, Px[k], Py[k], Pz[k]);
    tl[k][0]=X.f[9]; tl[k][1]=X.f[10]; tl[k][2]=X.f[11];
  }

  // ---- in-wave inclusive scan (Hillis-Steele, non-commutative) ----
  #pragma unroll
  for (int off = 1; off < 64; off <<= 1){
    Xf o;
    #pragma unroll
    for (int i = 0; i < 12; ++i) o.f[i] = __shfl_up(X.f[i], off);
    if (ln >= off) X = xcombine(o, X);
  }

  // half-0 publishes its chain-half total for the cross-wave prefix
  if (half == 0 && ln == 63){
    #pragma unroll
    for (int i = 0; i < 12; ++i) Tbuf[c][i] = X.f[i];
  }

  Xf E;
  #pragma unroll
  for (int i = 0; i < 12; ++i) E.f[i] = __shfl_up(X.f[i], 1);
  if (ln == 0) E = xident();

  __syncthreads();   // Tbuf visible; staged reads long done (Ls[0] now dead)

  if (half == 1){    // prepend half-0 total (ln==0: E=ident -> E=T)
    Xf T;
    #pragma unroll
    for (int i = 0; i < 12; ++i) T.f[i] = Tbuf[c][i];
    E = xcombine(T, E);
  }

  // ---- fold (F0, a2): G = F0*E.M ; G.t = a2 + F0*E.t ----
  const float bl0 = fmaf(rb0,  1.05f, 1.95f);
  const float d0  = fmaf(rd0,  1.75f, 3.25f);
  const float b1f = fmaf(rb1w, 1.05f, 1.95f);
  float ct0 = (bl0*bl0 + b1f*b1f - d0*d0) * frcp(2.0f*bl0*b1f);
  ct0 = fminf(fmaxf(ct0, -1.0f + EPSF), 1.0f - EPSF);
  const float st0 = sqrtf(fmaxf(1.0f - ct0*ct0, 0.0f));
  const float a1x = bl0;
  const float a2x = bl0 - b1f*ct0;
  const float a2y = b1f*st0;

  Xf G;   // F0 rows: (-ct0,-st0,0),(st0,-ct0,0),(0,0,1) applied to each column + t
  #pragma unroll
  for (int c3 = 0; c3 < 12; c3 += 3){
    const float ex = E.f[c3], ey = E.f[c3+1], ez = E.f[c3+2];
    G.f[c3]   = -ct0*ex - st0*ey;
    G.f[c3+1] =  st0*ex - ct0*ey;
    G.f[c3+2] =  ez;
  }
  G.f[9] += a2x; G.f[10] += a2y;

  // ---- positions p_k = G.t + G.M * tl[k]  (in place) ----
  #pragma unroll
  for (int k = 0; k < CHUNK; ++k){
    const float tx = tl[k][0], ty = tl[k][1], tz = tl[k][2];
    tl[k][0] = G.f[9]  + G.f[0]*tx + G.f[3]*ty + G.f[6]*tz;
    tl[k][1] = G.f[10] + G.f[1]*tx + G.f[4]*ty + G.f[7]*tz;
    tl[k][2] = G.f[11] + G.f[2]*tx + G.f[5]*ty + G.f[8]*tz;
  }

  // ---- pred publishes positions into dead Ls[0] (pitch 25, max 3198 < 4096) ----
  float* __restrict__ pos = &Ls[0][0];
  if (c == 0){
    #pragma unroll
    for (int k = 0; k < CHUNK; ++k){
      if (j0 + k < NSTEP){
        const int o = lid*25 + 3*k;
        pos[o] = tl[k][0]; pos[o+1] = tl[k][1]; pos[o+2] = tl[k][2];
      }
    }
    if (lid == 0){ ini[0] = a1x; ini[1] = a2x; ini[2] = a2y; }
  }
  __syncthreads();

  // ---- targ waves: diff + reduce ----
  float acc = 0.0f;
  if (c == 1){
    if (lid == 0){
      const float dx = ini[0] - a1x;   // a1 differs only in x; a0 diff = 0
      const float dy = ini[1] - a2x;   // a2 differs in x,y (z = 0)
      const float dz = ini[2] - a2y;
      acc = dx*dx + dy*dy + dz*dz;
    }
    #pragma unroll
    for (int k = 0; k < CHUNK; ++k){
      if (j0 + k < NSTEP){
        const int o = lid*25 + 3*k;
        const float dx = pos[o]   - tl[k][0];
        const float dy = pos[o+1] - tl[k][1];
        const float dz = pos[o+2] - tl[k][2];
        acc = fmaf(dx, dx, acc);
        acc = fmaf(dy, dy, acc);
        acc = fmaf(dz, dz, acc);
      }
    }
    #pragma unroll
    for (int off = 32; off > 0; off >>= 1) acc += __shfl_down(acc, off);
    if (half == 1 && ln == 0) part = acc;   // targ half-1 partial
  }
  __syncthreads();
  // plain store, zero contention (atomic drain was the 43us floor, R17)
  if (wv == 2 && ln == 0) ws[row] = acc + part;
}

// 1 block: reduce 2048 per-row partials -> out. 8 coalesced loads/thread.
__global__ void __launch_bounds__(256, 1)
reduce_kernel(const float* __restrict__ ws, float* __restrict__ out){
  __shared__ float wsum[4];
  const int tid = threadIdx.x;
  float a = 0.0f;
  #pragma unroll
  for (int i = 0; i < 8; ++i) a += ws[tid + (i << 8)];
  #pragma unroll
  for (int off = 32; off > 0; off >>= 1) a += __shfl_down(a, off);
  if ((tid & 63) == 0) wsum[tid >> 6] = a;
  __syncthreads();
  if (tid == 0) out[0] = (wsum[0] + wsum[1] + wsum[2] + wsum[3]) * INVMEAN;
}

extern "C" void kernel_launch(void* const* d_in, const int* in_sizes, int n_in,
                              void* d_out, int out_size, void* d_ws, size_t ws_size,
                              hipStream_t stream) {
  const float* pred = (const float*)d_in[0];
  const float* targ = (const float*)d_in[1];
  float* out = (float*)d_out;
  float* ws  = (float*)d_ws;   // needs 2048 floats = 8 KB

  rmsd_kernel<<<NROW, 256, 0, stream>>>(pred, targ, ws);
  reduce_kernel<<<1, 256, 0, stream>>>(ws, out);
}

// Round 9
// 102.148 us; speedup vs baseline: 1.0619x; 1.0619x over previous
//
#include <hip/hip_runtime.h>

// rmsdLoss via associative affine scan — R19.
// R18 null (staging repaid in LDS ops) -> kernel ~33us is ~60% VALU-issue-
// bound; all stall theories (occupancy R15, L1 R18, registers R14) null.
// R19 cuts VALU work ~20-25% via algebra, base = R17 (no staging, ws store):
//  1) Closed-form step rotation: P = b2*h with h=(-ct, st*ccv, st*scv) UNIT
//     -> q=1/b2, ist=rsqrt(1-ct^2) precomputable; xstepP's 2 rsqrt + length
//     math vanish. Identities (verified): M*c1step = ist*(hx*n0 - c0_old),
//     M*c2step = ccv*c2_old - scv*c1_old. Per-step 42->24 ops, trans 6->3.
//  2) ir = frsq(r2) (1 trans, was rcp+sqrt).
//  3) 6-float rotation scan (c2=c0xc1 reconstructed per combine; rotations
//     proper, proven) + commutative 3-float translation sum-scan after one
//     rotate by the exclusive prefix (R12-verified). Shuffles 84->60.
//  4) Compose unguarded (lane-127-only garbage, bounded, unconsumed).
// Predicted: dur_us 108.3 -> ~101-105 (kernel ~26-29us). If <1.5us delta ->
// instruction count not the limiter -> pivot to pipelining/packed-f32.

#define LROW  4087
#define NSTEP 1021
#define NROW  2048
#define CHUNK 8
#define EPSF  1e-6f
#define INVMEAN (1.0f / (2048.0f * 1024.0f * 3.0f))

__device__ __forceinline__ float frcp(float x){ return __builtin_amdgcn_rcpf(x); }
__device__ __forceinline__ float frsq(float x){ return __builtin_amdgcn_rsqf(x); }

__global__ void __launch_bounds__(256, 4)
rmsd_kernel(const float* __restrict__ pred, const float* __restrict__ targ,
            float* __restrict__ ws){
  __shared__ float pos[128*25 + 8];   // pitch 25: 12.8 KB
  __shared__ float Tbuf[2][12];       // per-chain half-0 totals: c0,c1,s (9 used)
  __shared__ float ini[3];            // pred a1x, a2x, a2y
  __shared__ float part;              // targ half-1 reduced partial

  const int row  = blockIdx.x;
  const int tid  = threadIdx.x;
  const int ln   = tid & 63;
  const int wv   = tid >> 6;          // 0..3
  const int c    = wv >> 1;           // 0 = pred, 1 = targ
  const int half = wv & 1;            // which half of the chain
  const int lid  = (half << 6) | ln;  // 0..127 lane-in-chain
  const int j0   = lid * CHUNK;       // first step owned (<= 1016)

  const float* __restrict__ v = (c ? targ : pred) + (size_t)row * LROW;
  const float cl = c ? 1e30f : 1.0f;  // reference clips pred only

  // broadcast fold inputs (wave-uniform -> scalar loads)
  const float rb0 = fminf(fmaxf(v[3064], -cl), cl);
  const float rd0 = fminf(fmaxf(v[2042], -cl), cl);
  const float rb1w= fminf(fmaxf(v[3065], -cl), cl);

  // ---- batch per-lane loads: 33 contiguous dwords, all independent ----
  float s0[CHUNK], s1[CHUNK], dd[CHUNK], bv[CHUNK+1];
  #pragma unroll
  for (int k = 0; k < CHUNK; ++k){
    s0[k] = v[2*(j0+k)];
    s1[k] = v[2*(j0+k)+1];
    dd[k] = v[2043 + j0 + k];
  }
  #pragma unroll
  for (int m = 0; m <= CHUNK; ++m){
    int ix = 3065 + j0 + m;
    if (ix > 4086) ix = 4086;        // tail lane clamp (garbage bounded)
    bv[m] = v[ix];
  }
  #pragma unroll
  for (int m = 0; m <= CHUNK; ++m)
    bv[m] = fmaf(fminf(fmaxf(bv[m], -cl), cl), 1.05f, 1.95f);

  // ---- fused build + compose (closed-form steps), snapshot translations ----
  float c0x,c0y,c0z, c1x,c1y,c1z, c2x,c2y,c2z, tx,ty,tz;
  float tl[CHUNK][3];
  #pragma unroll
  for (int k = 0; k < CHUNK; ++k){
    const float a0 = fminf(fmaxf(s0[k], -cl), cl);
    const float a1 = fminf(fmaxf(s1[k], -cl), cl);
    const float d  = fmaf(fminf(fmaxf(dd[k], -cl), cl), 1.75f, 3.25f);
    const float b1 = bv[k], b2 = bv[k+1];
    float ct = (b1*b1 + b2*b2 - d*d) * frcp(2.0f*b1*b2);
    ct = fminf(fmaxf(ct, -1.0f + EPSF), 1.0f - EPSF);
    const float omc = fmaxf(1.0f - ct*ct, 1e-12f);
    const float ist = frsq(omc);           // 1/st
    const float st  = omc * ist;           // sqrt(omc), no extra trans
    const float r2 = a0*a0 + a1*a1;
    const bool ok = r2 > 1e-36f;
    const float ir = ok ? frsq(r2) : 0.0f;
    const float scv = a0 * ir;                 // sin(chi)
    const float ccv = ok ? a1 * ir : 1.0f;     // cos(chi)
    const float hx = -ct, hy = st*ccv, hz = st*scv;   // unit step dir
    if (k == 0){
      c0x=hx;      c0y=hy;      c0z=hz;
      c1x=-st;     c1y=hx*ccv;  c1z=hx*scv;
      c2x=0.0f;    c2y=-scv;    c2z=ccv;
      tx=b2*hx;    ty=b2*hy;    tz=b2*hz;
    } else {
      // n0 = M*h
      const float n0x = c0x*hx + c1x*hy + c2x*hz;
      const float n0y = c0y*hx + c1y*hy + c2y*hz;
      const float n0z = c0z*hx + c1z*hy + c2z*hz;
      tx = fmaf(b2, n0x, tx); ty = fmaf(b2, n0y, ty); tz = fmaf(b2, n0z, tz);
      // n1 = ist*(hx*n0 - c0)
      const float n1x = ist * fmaf(hx, n0x, -c0x);
      const float n1y = ist * fmaf(hx, n0y, -c0y);
      const float n1z = ist * fmaf(hx, n0z, -c0z);
      // n2 = ccv*c2 - scv*c1
      const float n2x = fmaf(ccv, c2x, -scv*c1x);
      const float n2y = fmaf(ccv, c2y, -scv*c1y);
      const float n2z = fmaf(ccv, c2z, -scv*c1z);
      c0x=n0x; c0y=n0y; c0z=n0z;
      c1x=n1x; c1y=n1y; c1z=n1z;
      c2x=n2x; c2y=n2y; c2z=n2z;
    }
    tl[k][0]=tx; tl[k][1]=ty; tl[k][2]=tz;
  }

  // ---- in-wave inclusive ROTATION scan (6-float state, c2 reconstructed) ----
  float r0x=c0x, r0y=c0y, r0z=c0z, r1x=c1x, r1y=c1y, r1z=c1z;
  #pragma unroll
  for (int off = 1; off < 64; off <<= 1){
    const float o0x=__shfl_up(r0x,off), o0y=__shfl_up(r0y,off), o0z=__shfl_up(r0z,off);
    const float o1x=__shfl_up(r1x,off), o1y=__shfl_up(r1y,off), o1z=__shfl_up(r1z,off);
    const float o2x = o0y*o1z - o0z*o1y;
    const float o2y = o0z*o1x - o0x*o1z;
    const float o2z = o0x*o1y - o0y*o1x;
    const float n0x = o0x*r0x + o1x*r0y + o2x*r0z;
    const float n0y = o0y*r0x + o1y*r0y + o2y*r0z;
    const float n0z = o0z*r0x + o1z*r0y + o2z*r0z;
    const float n1x = o0x*r1x + o1x*r1y + o2x*r1z;
    const float n1y = o0y*r1x + o1y*r1y + o2y*r1z;
    const float n1z = o0z*r1x + o1z*r1y + o2z*r1z;
    if (ln >= off){
      r0x=n0x; r0y=n0y; r0z=n0z;
      r1x=n1x; r1y=n1y; r1z=n1z;
    }
  }

  // exclusive rotation prefix
  float e0x=__shfl_up(r0x,1), e0y=__shfl_up(r0y,1), e0z=__shfl_up(r0z,1);
  float e1x=__shfl_up(r1x,1), e1y=__shfl_up(r1y,1), e1z=__shfl_up(r1z,1);
  if (ln == 0){ e0x=1.f; e0y=0.f; e0z=0.f; e1x=0.f; e1y=1.f; e1z=0.f; }

  // ---- translation: w = E.M * t_chunk, then commutative 3-float sum scan ----
  {
    const float x2x = e0y*e1z - e0z*e1y;
    const float x2y = e0z*e1x - e0x*e1z;
    const float x2z = e0x*e1y - e0y*e1x;
    const float wx = e0x*tx + e1x*ty + x2x*tz;
    const float wy = e0y*tx + e1y*ty + x2y*tz;
    const float wz = e0z*tx + e1z*ty + x2z*tz;
    float sx=wx, sy=wy, sz=wz;
    #pragma unroll
    for (int off = 1; off < 64; off <<= 1){
      const float ax=__shfl_up(sx,off), ay=__shfl_up(sy,off), az=__shfl_up(sz,off);
      if (ln >= off){ sx+=ax; sy+=ay; sz+=az; }
    }
    tx = sx - wx; ty = sy - wy; tz = sz - wz;   // exclusive translation prefix

    // half-0 publishes chain-half totals: inclusive (r0,r1) + inclusive s
    if (half == 0 && ln == 63){
      Tbuf[c][0]=r0x; Tbuf[c][1]=r0y; Tbuf[c][2]=r0z;
      Tbuf[c][3]=r1x; Tbuf[c][4]=r1y; Tbuf[c][5]=r1z;
      Tbuf[c][6]=sx;  Tbuf[c][7]=sy;  Tbuf[c][8]=sz;
    }
  }
  __syncthreads();

  if (half == 1){    // prepend half-0 total: E = T o E_local
    const float T0x=Tbuf[c][0], T0y=Tbuf[c][1], T0z=Tbuf[c][2];
    const float T1x=Tbuf[c][3], T1y=Tbuf[c][4], T1z=Tbuf[c][5];
    const float T2x = T0y*T1z - T0z*T1y;
    const float T2y = T0z*T1x - T0x*T1z;
    const float T2z = T0x*T1y - T0y*T1x;
    const float f0x = T0x*e0x + T1x*e0y + T2x*e0z;
    const float f0y = T0y*e0x + T1y*e0y + T2y*e0z;
    const float f0z = T0z*e0x + T1z*e0y + T2z*e0z;
    const float f1x = T0x*e1x + T1x*e1y + T2x*e1z;
    const float f1y = T0y*e1x + T1y*e1y + T2y*e1z;
    const float f1z = T0z*e1x + T1z*e1y + T2z*e1z;
    const float ntx = Tbuf[c][6] + T0x*tx + T1x*ty + T2x*tz;
    const float nty = Tbuf[c][7] + T0y*tx + T1y*ty + T2y*tz;
    const float ntz = Tbuf[c][8] + T0z*tx + T1z*ty + T2z*tz;
    e0x=f0x; e0y=f0y; e0z=f0z; e1x=f1x; e1y=f1y; e1z=f1z;
    tx=ntx; ty=nty; tz=ntz;
  }

  // ---- fold (F0, a2): G = F0*E ; G.t = a2 + F0*E.t ----
  const float bl0 = fmaf(rb0,  1.05f, 1.95f);
  const float d0  = fmaf(rd0,  1.75f, 3.25f);
  const float b1f = fmaf(rb1w, 1.05f, 1.95f);
  float ct0 = (bl0*bl0 + b1f*b1f - d0*d0) * frcp(2.0f*bl0*b1f);
  ct0 = fminf(fmaxf(ct0, -1.0f + EPSF), 1.0f - EPSF);
  const float st0 = sqrtf(fmaxf(1.0f - ct0*ct0, 0.0f));
  const float a1x = bl0;
  const float a2x = bl0 - b1f*ct0;
  const float a2y = b1f*st0;

  const float e2x = e0y*e1z - e0z*e1y;
  const float e2y = e0z*e1x - e0x*e1z;
  const float e2z = e0x*e1y - e0y*e1x;

  // G columns: apply F0 rows (-ct0,-st0,0),(st0,-ct0,0),(0,0,1)
  const float g0x = -ct0*e0x - st0*e0y, g0y = st0*e0x - ct0*e0y, g0z = e0z;
  const float g1x = -ct0*e1x - st0*e1y, g1y = st0*e1x - ct0*e1y, g1z = e1z;
  const float g2x = -ct0*e2x - st0*e2y, g2y = st0*e2x - ct0*e2y, g2z = e2z;
  const float gtx = a2x - ct0*tx - st0*ty;
  const float gty = a2y + st0*tx - ct0*ty;
  const float gtz = tz;

  // ---- positions p_k = G.t + G.M * tl[k]  (in place) ----
  #pragma unroll
  for (int k = 0; k < CHUNK; ++k){
    const float ux = tl[k][0], uy = tl[k][1], uz = tl[k][2];
    tl[k][0] = gtx + g0x*ux + g1x*uy + g2x*uz;
    tl[k][1] = gty + g0y*ux + g1y*uy + g2y*uz;
    tl[k][2] = gtz + g0z*ux + g1z*uy + g2z*uz;
  }

  // ---- pred publishes positions (pitch 25 -> conflict-free) ----
  if (c == 0){
    #pragma unroll
    for (int k = 0; k < CHUNK; ++k){
      if (j0 + k < NSTEP){
        const int o = lid*25 + 3*k;
        pos[o] = tl[k][0]; pos[o+1] = tl[k][1]; pos[o+2] = tl[k][2];
      }
    }
    if (lid == 0){ ini[0] = a1x; ini[1] = a2x; ini[2] = a2y; }
  }
  __syncthreads();

  // ---- targ waves: diff + reduce ----
  float acc = 0.0f;
  if (c == 1){
    if (lid == 0){
      const float dx = ini[0] - a1x;   // a1 differs only in x; a0 diff = 0
      const float dy = ini[1] - a2x;   // a2 differs in x,y (z = 0)
      const float dz = ini[2] - a2y;
      acc = dx*dx + dy*dy + dz*dz;
    }
    #pragma unroll
    for (int k = 0; k < CHUNK; ++k){
      if (j0 + k < NSTEP){
        const int o = lid*25 + 3*k;
        const float dx = pos[o]   - tl[k][0];
        const float dy = pos[o+1] - tl[k][1];
        const float dz = pos[o+2] - tl[k][2];
        acc = fmaf(dx, dx, acc);
        acc = fmaf(dy, dy, acc);
        acc = fmaf(dz, dz, acc);
      }
    }
    #pragma unroll
    for (int off = 32; off > 0; off >>= 1) acc += __shfl_down(acc, off);
    if (half == 1 && ln == 0) part = acc;   // targ half-1 partial
  }
  __syncthreads();
  // plain store, zero contention (atomic drain cost ~11us, removed in R17)
  if (wv == 2 && ln == 0) ws[row] = acc + part;
}

// 1 block: reduce 2048 per-row partials -> out. 8 coalesced loads/thread.
__global__ void __launch_bounds__(256, 1)
reduce_kernel(const float* __restrict__ ws, float* __restrict__ out){
  __shared__ float wsum[4];
  const int tid = threadIdx.x;
  float a = 0.0f;
  #pragma unroll
  for (int i = 0; i < 8; ++i) a += ws[tid + (i << 8)];
  #pragma unroll
  for (int off = 32; off > 0; off >>= 1) a += __shfl_down(a, off);
  if ((tid & 63) == 0) wsum[tid >> 6] = a;
  __syncthreads();
  if (tid == 0) out[0] = (wsum[0] + wsum[1] + wsum[2] + wsum[3]) * INVMEAN;
}

extern "C" void kernel_launch(void* const* d_in, const int* in_sizes, int n_in,
                              void* d_out, int out_size, void* d_ws, size_t ws_size,
                              hipStream_t stream) {
  const float* pred = (const float*)d_in[0];
  const float* targ = (const float*)d_in[1];
  float* out = (float*)d_out;
  float* ws  = (float*)d_ws;   // needs 2048 floats = 8 KB

  rmsd_kernel<<<NROW, 256, 0, stream>>>(pred, targ, ws);
  reduce_kernel<<<1, 256, 0, stream>>>(ws, out);
}

// Round 10
// 96.730 us; speedup vs baseline: 1.1214x; 1.0560x over previous
//
#include <hip/hip_runtime.h>

// rmsdLoss via associative affine scan — R20.
// R19 confirmed VALU-issue-bound (algebra cut -22% work -> -19% time).
// R20 amortizes the per-thread-CONSTANT scan cost (~300 instr) over bigger
// chunks: CHUNK=16, ONE wave per chain, block = 128 thr (wv0 pred, wv1 targ).
// Total VALU/row: 256x(336+300+150)=202K -> 128x(672+300+150)=143K (-30%),
// and the cross-wave combine (Tbuf + 1 barrier) disappears.
// This is R10's geometry, but R10 was measured under the 43us atomic floor
// AND with 32B/thread spills — its merits were never observed.
// Spill countermeasure (R12 lesson: allocator spills chasing the 64-reg/
// 8-wave tier): amdgpu_waves_per_eu(4,4) pins occupancy at 4 waves/EU so
// the 64-reg tier buys nothing -> allocator free to use ~90/128 VGPR.
// Tail: lane 63 steps 1021..1023 garbage-but-finite (clamps bound inputs,
// frcp args >= 2*0.81), flow only into guarded tl slots + unconsumed scan top.
// Predicted: dur_us 102.1 -> ~95-98 (kernel ~27 -> ~20-23us). If flat/worse:
// spills -> re-pin or revert geometry.

#define LROW  4087
#define NSTEP 1021
#define NROW  2048
#define CHUNK 16
#define EPSF  1e-6f
#define INVMEAN (1.0f / (2048.0f * 1024.0f * 3.0f))

__device__ __forceinline__ float frcp(float x){ return __builtin_amdgcn_rcpf(x); }
__device__ __forceinline__ float frsq(float x){ return __builtin_amdgcn_rsqf(x); }

__global__ void __launch_bounds__(128) __attribute__((amdgpu_waves_per_eu(4, 4)))
rmsd_kernel(const float* __restrict__ pred, const float* __restrict__ targ,
            float* __restrict__ ws){
  __shared__ float pos[64*49 + 48 + 2];  // pitch 49: 12.9 KB
  __shared__ float ini[3];               // pred a1x, a2x, a2y

  const int row  = blockIdx.x;
  const int tid  = threadIdx.x;
  const int ln   = tid & 63;
  const int wv   = tid >> 6;          // 0 = pred, 1 = targ
  const int j0   = ln * CHUNK;        // first step owned (<= 1008)

  const float* __restrict__ v = (wv ? targ : pred) + (size_t)row * LROW;
  const float cl = wv ? 1e30f : 1.0f; // reference clips pred only

  // broadcast fold inputs (wave-uniform -> scalar loads)
  const float rb0 = fminf(fmaxf(v[3064], -cl), cl);
  const float rd0 = fminf(fmaxf(v[2042], -cl), cl);
  const float rb1w= fminf(fmaxf(v[3065], -cl), cl);

  // ---- batch per-lane loads: 65 contiguous dwords, all independent ----
  float s0[CHUNK], s1[CHUNK], dd[CHUNK], bv[CHUNK+1];
  #pragma unroll
  for (int k = 0; k < CHUNK; ++k){
    s0[k] = v[2*(j0+k)];
    s1[k] = v[2*(j0+k)+1];
    dd[k] = v[2043 + j0 + k];        // lane63 k>=13: reads 3064.. (valid mem, garbage steps guarded)
  }
  #pragma unroll
  for (int m = 0; m <= CHUNK; ++m){
    int ix = 3065 + j0 + m;
    if (ix > 4086) ix = 4086;        // tail lane clamp (garbage bounded)
    bv[m] = v[ix];
  }
  #pragma unroll
  for (int m = 0; m <= CHUNK; ++m)
    bv[m] = fmaf(fminf(fmaxf(bv[m], -cl), cl), 1.05f, 1.95f);

  // ---- fused build + compose (closed-form steps), snapshot translations ----
  float c0x,c0y,c0z, c1x,c1y,c1z, c2x,c2y,c2z, tx,ty,tz;
  float tl[CHUNK][3];
  #pragma unroll
  for (int k = 0; k < CHUNK; ++k){
    const float a0 = fminf(fmaxf(s0[k], -cl), cl);
    const float a1 = fminf(fmaxf(s1[k], -cl), cl);
    const float d  = fmaf(fminf(fmaxf(dd[k], -cl), cl), 1.75f, 3.25f);
    const float b1 = bv[k], b2 = bv[k+1];
    float ct = (b1*b1 + b2*b2 - d*d) * frcp(2.0f*b1*b2);
    ct = fminf(fmaxf(ct, -1.0f + EPSF), 1.0f - EPSF);
    const float omc = fmaxf(1.0f - ct*ct, 1e-12f);
    const float ist = frsq(omc);           // 1/st
    const float st  = omc * ist;           // sqrt(omc), no extra trans
    const float r2 = a0*a0 + a1*a1;
    const bool ok = r2 > 1e-36f;
    const float ir = ok ? frsq(r2) : 0.0f;
    const float scv = a0 * ir;                 // sin(chi)
    const float ccv = ok ? a1 * ir : 1.0f;     // cos(chi)
    const float hx = -ct, hy = st*ccv, hz = st*scv;   // unit step dir
    if (k == 0){
      c0x=hx;      c0y=hy;      c0z=hz;
      c1x=-st;     c1y=hx*ccv;  c1z=hx*scv;
      c2x=0.0f;    c2y=-scv;    c2z=ccv;
      tx=b2*hx;    ty=b2*hy;    tz=b2*hz;
    } else {
      // n0 = M*h
      const float n0x = c0x*hx + c1x*hy + c2x*hz;
      const float n0y = c0y*hx + c1y*hy + c2y*hz;
      const float n0z = c0z*hx + c1z*hy + c2z*hz;
      tx = fmaf(b2, n0x, tx); ty = fmaf(b2, n0y, ty); tz = fmaf(b2, n0z, tz);
      // n1 = ist*(hx*n0 - c0)
      const float n1x = ist * fmaf(hx, n0x, -c0x);
      const float n1y = ist * fmaf(hx, n0y, -c0y);
      const float n1z = ist * fmaf(hx, n0z, -c0z);
      // n2 = ccv*c2 - scv*c1
      const float n2x = fmaf(ccv, c2x, -scv*c1x);
      const float n2y = fmaf(ccv, c2y, -scv*c1y);
      const float n2z = fmaf(ccv, c2z, -scv*c1z);
      c0x=n0x; c0y=n0y; c0z=n0z;
      c1x=n1x; c1y=n1y; c1z=n1z;
      c2x=n2x; c2y=n2y; c2z=n2z;
    }
    tl[k][0]=tx; tl[k][1]=ty; tl[k][2]=tz;
  }

  // ---- in-wave inclusive ROTATION scan (6-float state, c2 reconstructed) ----
  float r0x=c0x, r0y=c0y, r0z=c0z, r1x=c1x, r1y=c1y, r1z=c1z;
  #pragma unroll
  for (int off = 1; off < 64; off <<= 1){
    const float o0x=__shfl_up(r0x,off), o0y=__shfl_up(r0y,off), o0z=__shfl_up(r0z,off);
    const float o1x=__shfl_up(r1x,off), o1y=__shfl_up(r1y,off), o1z=__shfl_up(r1z,off);
    const float o2x = o0y*o1z - o0z*o1y;
    const float o2y = o0z*o1x - o0x*o1z;
    const float o2z = o0x*o1y - o0y*o1x;
    const float n0x = o0x*r0x + o1x*r0y + o2x*r0z;
    const float n0y = o0y*r0x + o1y*r0y + o2y*r0z;
    const float n0z = o0z*r0x + o1z*r0y + o2z*r0z;
    const float n1x = o0x*r1x + o1x*r1y + o2x*r1z;
    const float n1y = o0y*r1x + o1y*r1y + o2y*r1z;
    const float n1z = o0z*r1x + o1z*r1y + o2z*r1z;
    if (ln >= off){
      r0x=n0x; r0y=n0y; r0z=n0z;
      r1x=n1x; r1y=n1y; r1z=n1z;
    }
  }

  // exclusive rotation prefix
  float e0x=__shfl_up(r0x,1), e0y=__shfl_up(r0y,1), e0z=__shfl_up(r0z,1);
  float e1x=__shfl_up(r1x,1), e1y=__shfl_up(r1y,1), e1z=__shfl_up(r1z,1);
  if (ln == 0){ e0x=1.f; e0y=0.f; e0z=0.f; e1x=0.f; e1y=1.f; e1z=0.f; }

  // ---- translation: w = E.M * t_chunk, then commutative 3-float sum scan ----
  {
    const float x2x = e0y*e1z - e0z*e1y;
    const float x2y = e0z*e1x - e0x*e1z;
    const float x2z = e0x*e1y - e0y*e1x;
    const float wx = e0x*tx + e1x*ty + x2x*tz;
    const float wy = e0y*tx + e1y*ty + x2y*tz;
    const float wz = e0z*tx + e1z*ty + x2z*tz;
    float sx=wx, sy=wy, sz=wz;
    #pragma unroll
    for (int off = 1; off < 64; off <<= 1){
      const float ax=__shfl_up(sx,off), ay=__shfl_up(sy,off), az=__shfl_up(sz,off);
      if (ln >= off){ sx+=ax; sy+=ay; sz+=az; }
    }
    tx = sx - wx; ty = sy - wy; tz = sz - wz;   // exclusive translation prefix
  }

  // ---- fold (F0, a2): G = F0*E ; G.t = a2 + F0*E.t ----
  const float bl0 = fmaf(rb0,  1.05f, 1.95f);
  const float d0  = fmaf(rd0,  1.75f, 3.25f);
  const float b1f = fmaf(rb1w, 1.05f, 1.95f);
  float ct0 = (bl0*bl0 + b1f*b1f - d0*d0) * frcp(2.0f*bl0*b1f);
  ct0 = fminf(fmaxf(ct0, -1.0f + EPSF), 1.0f - EPSF);
  const float st0 = sqrtf(fmaxf(1.0f - ct0*ct0, 0.0f));
  const float a1x = bl0;
  const float a2x = bl0 - b1f*ct0;
  const float a2y = b1f*st0;

  const float e2x = e0y*e1z - e0z*e1y;
  const float e2y = e0z*e1x - e0x*e1z;
  const float e2z = e0x*e1y - e0y*e1x;

  // G columns: apply F0 rows (-ct0,-st0,0),(st0,-ct0,0),(0,0,1)
  const float g0x = -ct0*e0x - st0*e0y, g0y = st0*e0x - ct0*e0y, g0z = e0z;
  const float g1x = -ct0*e1x - st0*e1y, g1y = st0*e1x - ct0*e1y, g1z = e1z;
  const float g2x = -ct0*e2x - st0*e2y, g2y = st0*e2x - ct0*e2y, g2z = e2z;
  const float gtx = a2x - ct0*tx - st0*ty;
  const float gty = a2y + st0*tx - ct0*ty;
  const float gtz = tz;

  // ---- positions p_k = G.t + G.M * tl[k]  (in place) ----
  #pragma unroll
  for (int k = 0; k < CHUNK; ++k){
    const float ux = tl[k][0], uy = tl[k][1], uz = tl[k][2];
    tl[k][0] = gtx + g0x*ux + g1x*uy + g2x*uz;
    tl[k][1] = gty + g0y*ux + g1y*uy + g2y*uz;
    tl[k][2] = gtz + g0z*ux + g1z*uy + g2z*uz;
  }

  // ---- pred publishes positions (pitch 49) ----
  if (wv == 0){
    #pragma unroll
    for (int k = 0; k < CHUNK; ++k){
      if (j0 + k < NSTEP){
        const int o = ln*49 + 3*k;
        pos[o] = tl[k][0]; pos[o+1] = tl[k][1]; pos[o+2] = tl[k][2];
      }
    }
    if (ln == 0){ ini[0] = a1x; ini[1] = a2x; ini[2] = a2y; }
  }
  __syncthreads();

  // ---- targ wave: diff + reduce ----
  if (wv == 1){
    float acc = 0.0f;
    if (ln == 0){
      const float dx = ini[0] - a1x;   // a1 differs only in x; a0 diff = 0
      const float dy = ini[1] - a2x;   // a2 differs in x,y (z = 0)
      const float dz = ini[2] - a2y;
      acc = dx*dx + dy*dy + dz*dz;
    }
    #pragma unroll
    for (int k = 0; k < CHUNK; ++k){
      if (j0 + k < NSTEP){
        const int o = ln*49 + 3*k;
        const float dx = pos[o]   - tl[k][0];
        const float dy = pos[o+1] - tl[k][1];
        const float dz = pos[o+2] - tl[k][2];
        acc = fmaf(dx, dx, acc);
        acc = fmaf(dy, dy, acc);
        acc = fmaf(dz, dz, acc);
      }
    }
    #pragma unroll
    for (int off = 32; off > 0; off >>= 1) acc += __shfl_down(acc, off);
    // plain store, zero contention (atomic drain was the 43us floor, R17)
    if (ln == 0) ws[row] = acc;
  }
}

// 1 block: reduce 2048 per-row partials -> out. 8 coalesced loads/thread.
__global__ void __launch_bounds__(256, 1)
reduce_kernel(const float* __restrict__ ws, float* __restrict__ out){
  __shared__ float wsum[4];
  const int tid = threadIdx.x;
  float a = 0.0f;
  #pragma unroll
  for (int i = 0; i < 8; ++i) a += ws[tid + (i << 8)];
  #pragma unroll
  for (int off = 32; off > 0; off >>= 1) a += __shfl_down(a, off);
  if ((tid & 63) == 0) wsum[tid >> 6] = a;
  __syncthreads();
  if (tid == 0) out[0] = (wsum[0] + wsum[1] + wsum[2] + wsum[3]) * INVMEAN;
}

extern "C" void kernel_launch(void* const* d_in, const int* in_sizes, int n_in,
                              void* d_out, int out_size, void* d_ws, size_t ws_size,
                              hipStream_t stream) {
  const float* pred = (const float*)d_in[0];
  const float* targ = (const float*)d_in[1];
  float* out = (float*)d_out;
  float* ws  = (float*)d_ws;   // needs 2048 floats = 8 KB

  rmsd_kernel<<<NROW, 128, 0, stream>>>(pred, targ, ws);
  reduce_kernel<<<1, 256, 0, stream>>>(ws, out);
}